// Round 3
// baseline (1246.040 us; speedup 1.0000x reference)
//
#include <hip/hip_runtime.h>

#define B_   32
#define T_   300
#define C1_  2312
#define O1_  512
#define O2_  512
#define O3_  10
#define M_   (B_*T_)   // 9600

// ---------------- weight prep (all f64) ----------------

__global__ void calc_f(const float* __restrict__ v, const float* __restrict__ g,
                       double* __restrict__ f, int O, int C) {
    int o = blockIdx.x;
    const float* row = v + (size_t)o * C;
    double s = 0.0;
    for (int c = threadIdx.x; c < C; c += blockDim.x) {
        double x = (double)row[c];
        s += x * x;
    }
    for (int off = 32; off; off >>= 1) s += __shfl_down(s, off);
    __shared__ double wsum[4];
    int lane = threadIdx.x & 63, wv = threadIdx.x >> 6;
    if (lane == 0) wsum[wv] = s;
    __syncthreads();
    if (threadIdx.x == 0) {
        double tot = 0.0;
        for (int i = 0; i < (int)(blockDim.x >> 6); ++i) tot += wsum[i];
        f[o] = (double)g[o] / sqrt(tot);
    }
}

// wt[c*ldo + o] = v[o*C + c] * f[o]   (double)
__global__ void transpose_scale(const float* __restrict__ v, const double* __restrict__ f,
                                double* __restrict__ wt, int O, int C, int ldo) {
    __shared__ double tile[32][33];
    int c0 = blockIdx.x * 32, o0 = blockIdx.y * 32;
    int tx = threadIdx.x, ty = threadIdx.y;
    for (int k = 0; k < 4; ++k) {
        int o = o0 + ty + k * 8, c = c0 + tx;
        double val = 0.0;
        if (o < O && c < C) val = (double)v[(size_t)o * C + c] * f[o];
        tile[ty + k * 8][tx] = val;
    }
    __syncthreads();
    for (int k = 0; k < 4; ++k) {
        int c = c0 + ty + k * 8, o = o0 + tx;
        if (c < C && o < O) wt[(size_t)c * ldo + o] = tile[tx][ty + k * 8];
    }
}

// ---------------- GEMM layer 1 (f64 acc) ----------------
// X: spike [B, C1, T] f32 ; Wt: [C1, O1] f64 ; Z: [B, T, O1] f64
// tile: 128 o x 64 t, 256 threads, micro 4(o) x 8(t): to=tid&31, tt=tid>>5
__global__ __launch_bounds__(256) void gemm1(const float* __restrict__ X,
                                             const double* __restrict__ Wt,
                                             double* __restrict__ Z) {
    __shared__ double Ws[16][128];
    __shared__ double Xs[16][64];
    int b  = blockIdx.z;
    int t0 = blockIdx.x * 64;
    int o0 = blockIdx.y * 128;
    int tid = threadIdx.x;
    int to = tid & 31, tt = tid >> 5;
    double acc[4][8];
#pragma unroll
    for (int i = 0; i < 4; ++i)
#pragma unroll
        for (int j = 0; j < 8; ++j) acc[i][j] = 0.0;
    const float* Xb = X + (size_t)b * C1_ * T_;
    for (int c0 = 0; c0 < C1_; c0 += 16) {
        {   // Xs: 16x64 from f32, one float4/thread (j multiple of 4, T%4==0)
            int e = tid * 4;
            int i = e >> 6, j = e & 63;
            int c = c0 + i, t = t0 + j;
            float4 val = make_float4(0.f, 0.f, 0.f, 0.f);
            if (c < C1_ && t < T_) val = *(const float4*)(Xb + (size_t)c * T_ + t);
            Xs[i][j]     = (double)val.x;
            Xs[i][j + 1] = (double)val.y;
            Xs[i][j + 2] = (double)val.z;
            Xs[i][j + 3] = (double)val.w;
        }
#pragma unroll
        for (int r = 0; r < 4; ++r) {   // Ws: 16x128 doubles, 4 double2/thread
            int idx = r * 256 + tid;
            int i = idx >> 6, od = (idx & 63) * 2;
            int c = c0 + i;
            double2 val = make_double2(0.0, 0.0);
            if (c < C1_) val = *(const double2*)(Wt + (size_t)c * O1_ + o0 + od);
            *(double2*)(&Ws[i][od]) = val;
        }
        __syncthreads();
#pragma unroll
        for (int k = 0; k < 16; ++k) {
            double wf[4], xf[8];
#pragma unroll
            for (int i = 0; i < 4; ++i) wf[i] = Ws[k][to * 4 + i];
#pragma unroll
            for (int j = 0; j < 8; ++j) xf[j] = Xs[k][tt * 8 + j];
#pragma unroll
            for (int i = 0; i < 4; ++i)
#pragma unroll
                for (int j = 0; j < 8; ++j) acc[i][j] += wf[i] * xf[j];
        }
        __syncthreads();
    }
#pragma unroll
    for (int j = 0; j < 8; ++j) {
        int t = t0 + tt * 8 + j;
        if (t < T_) {
            double* dst = Z + ((size_t)b * T_ + t) * O1_ + o0 + to * 4;
            dst[0] = acc[0][j]; dst[1] = acc[1][j];
            dst[2] = acc[2][j]; dst[3] = acc[3][j];
        }
    }
}

// ---------------- GEMM layer 2 (f64 acc) ----------------
// A: s1 [M, 512] f32 (exact 0/1) ; Wt: [512, 512] f64 ; Z: [M, 512] f64
// tile 64m x 128n, 256 threads, micro 8(m) x 4(n): tn=tid&31, tm=tid>>5
__global__ __launch_bounds__(256) void gemm2(const float* __restrict__ A,
                                             const double* __restrict__ Wt,
                                             double* __restrict__ Z) {
    __shared__ double As[16][64];
    __shared__ double Bs[16][128];
    int m0 = blockIdx.x * 64, n0 = blockIdx.y * 128;
    int tid = threadIdx.x;
    int tn = tid & 31, tm = tid >> 5;
    double acc[8][4];
#pragma unroll
    for (int i = 0; i < 8; ++i)
#pragma unroll
        for (int j = 0; j < 4; ++j) acc[i][j] = 0.0;
    for (int c0 = 0; c0 < 512; c0 += 16) {
        {   // As: 16c x 64m (transposed), one float4/thread
            int m = tid >> 2, q = tid & 3;
            float4 val = *(const float4*)(A + (size_t)(m0 + m) * 512 + c0 + q * 4);
            As[q * 4 + 0][m] = (double)val.x;
            As[q * 4 + 1][m] = (double)val.y;
            As[q * 4 + 2][m] = (double)val.z;
            As[q * 4 + 3][m] = (double)val.w;
        }
#pragma unroll
        for (int r = 0; r < 4; ++r) {   // Bs: 16x128 doubles
            int idx = r * 256 + tid;
            int i = idx >> 6, od = (idx & 63) * 2;
            *(double2*)(&Bs[i][od]) = *(const double2*)(Wt + (size_t)(c0 + i) * 512 + n0 + od);
        }
        __syncthreads();
#pragma unroll
        for (int k = 0; k < 16; ++k) {
            double mf[8], nf[4];
#pragma unroll
            for (int i = 0; i < 8; ++i) mf[i] = As[k][tm * 8 + i];
#pragma unroll
            for (int j = 0; j < 4; ++j) nf[j] = Bs[k][tn * 4 + j];
#pragma unroll
            for (int i = 0; i < 8; ++i)
#pragma unroll
                for (int j = 0; j < 4; ++j) acc[i][j] += mf[i] * nf[j];
        }
        __syncthreads();
    }
#pragma unroll
    for (int i = 0; i < 8; ++i) {
        double* dst = Z + (size_t)(m0 + tm * 8 + i) * 512 + n0 + tn * 4;
        dst[0] = acc[i][0]; dst[1] = acc[i][1];
        dst[2] = acc[i][2]; dst[3] = acc[i][3];
    }
}

// ---------------- GEMM layer 3 (f64 acc) ----------------
// A: s2 [M, 512] f32 ; Wt: [512, 16] f64 (cols >=10 unused) ; Z: [M, 16] f64
__global__ __launch_bounds__(256) void gemm3(const float* __restrict__ A,
                                             const double* __restrict__ Wt,
                                             double* __restrict__ Z) {
    __shared__ double w[512 * 16];
    for (int e = threadIdx.x; e < 4096; e += 256)
        ((double2*)w)[e] = ((const double2*)Wt)[e];
    __syncthreads();
    int m = blockIdx.x * 256 + threadIdx.x;
    if (m >= M_) return;
    double acc[O3_];
#pragma unroll
    for (int o = 0; o < O3_; ++o) acc[o] = 0.0;
    const float4* Ar = (const float4*)(A + (size_t)m * 512);
    for (int cq = 0; cq < 128; ++cq) {
        float4 a = Ar[cq];
        float av[4] = {a.x, a.y, a.z, a.w};
#pragma unroll
        for (int u = 0; u < 4; ++u)
#pragma unroll
            for (int o = 0; o < O3_; ++o) acc[o] += (double)av[u] * w[(cq * 4 + u) * 16 + o];
    }
    double* dst = Z + (size_t)m * 16;
#pragma unroll
    for (int o = 0; o < O3_; ++o) dst[o] = acc[o];
}

// ---------------- LIF scan + delay, layers 1/2 (O=512, f64 state) ----------------
__global__ void scan12(const double* __restrict__ Zin,  // [B, T, 512] f64
                       const int* __restrict__ delay,   // [512]
                       float* __restrict__ Sout,        // [B, T, 512] f32 spikes
                       float* __restrict__ sumOut) {
    int o = blockIdx.x * 256 + threadIdx.x;
    int b = blockIdx.y;
    const double* z = Zin + (size_t)b * T_ * O1_ + o;
    float* s = Sout + (size_t)b * T_ * O1_ + o;
    int d = delay[o];
    for (int t = 0; t < d; ++t) s[(size_t)t * O1_] = 0.f;
    double cur = 0.0, vol = 0.0;
    float cnt = 0.f;
    for (int t = 0; t < T_; ++t) {
        cur = cur * 0.75 + z[(size_t)t * O1_];
        vol = vol * 0.97 + cur;
        float sp = (vol >= 1.25) ? 1.f : 0.f;
        if (sp > 0.f) vol = 0.0;
        int tw = t + d;
        if (tw < T_) { s[(size_t)tw * O1_] = sp; cnt += sp; }
    }
    for (int off = 32; off; off >>= 1) cnt += __shfl_down(cnt, off);
    if ((threadIdx.x & 63) == 0) atomicAdd(sumOut, cnt);
}

// ---------------- LIF scan + delay, layer 3 (O=10, f64 state) ----------------
__global__ void scan3(const double* __restrict__ Z3,  // [M, 16] f64
                      const int* __restrict__ d3,     // [10]
                      float* __restrict__ out,        // d_out: [B, 10, 300] f32
                      float* __restrict__ sumOut) {
    __shared__ double zt[T_ * 16];
    int b = blockIdx.x;
    const double2* src = (const double2*)(Z3 + (size_t)b * T_ * 16);
    for (int e = threadIdx.x; e < T_ * 8; e += 64)
        ((double2*)zt)[e] = src[e];
    __syncthreads();
    int o = threadIdx.x;
    if (o < O3_) {
        int d = d3[o];
        float* dst = out + (size_t)b * O3_ * T_ + (size_t)o * T_;
        for (int t = 0; t < d; ++t) dst[t] = 0.f;
        double cur = 0.0, vol = 0.0;
        float cnt = 0.f;
        for (int t = 0; t < T_; ++t) {
            cur = cur * 0.75 + zt[t * 16 + o];
            vol = vol * 0.97 + cur;
            float sp = (vol >= 1.25) ? 1.f : 0.f;
            if (sp > 0.f) vol = 0.0;
            int tw = t + d;
            if (tw < T_) { dst[tw] = sp; cnt += sp; }
        }
        atomicAdd(sumOut, cnt);
    }
}

__global__ void finalize(const float* __restrict__ sums, float* __restrict__ out) {
    if (threadIdx.x == 0) {
        out[0] = (float)((double)sums[0] / (double)(B_ * O1_ * T_));
        out[1] = (float)((double)sums[1] / (double)(B_ * O2_ * T_));
        out[2] = (float)((double)sums[2] / (double)(B_ * O3_ * T_));
    }
}

extern "C" void kernel_launch(void* const* d_in, const int* in_sizes, int n_in,
                              void* d_out, int out_size, void* d_ws, size_t ws_size,
                              hipStream_t stream) {
    const float* spike = (const float*)d_in[0];
    const float* v1 = (const float*)d_in[1];
    const float* g1 = (const float*)d_in[2];
    const float* v2 = (const float*)d_in[3];
    const float* g2 = (const float*)d_in[4];
    const float* v3 = (const float*)d_in[5];
    const float* g3 = (const float*)d_in[6];
    const int* d1 = (const int*)d_in[7];
    const int* d2 = (const int*)d_in[8];
    const int* d3 = (const int*)d_in[9];
    float* out = (float*)d_out;

    // Workspace: doubles first, then floats. Total ~71.9 MB.
    double* dw = (double*)d_ws;
    size_t off = 0;
    double* f1  = dw + off; off += 512;
    double* f2  = dw + off; off += 512;
    double* f3  = dw + off; off += 16;
    double* Wt1 = dw + off; off += (size_t)C1_ * O1_;   // [2312, 512]
    double* Wt2 = dw + off; off += 512 * 512;
    double* Wt3 = dw + off; off += 512 * 16;
    double* zA  = dw + off; off += (size_t)M_ * 512;    // f64 synapse currents
    double* z3b = dw + off; off += (size_t)M_ * 16;
    float* fw = (float*)(dw + off);
    float* sB   = fw;                                   // f32 spikes, M*512
    float* sums = fw + (size_t)M_ * 512;                // 4 floats
    (void)ws_size; (void)out_size; (void)in_sizes; (void)n_in;

    hipMemsetAsync(sums, 0, 4 * sizeof(float), stream);

    calc_f<<<512, 256, 0, stream>>>(v1, g1, f1, O1_, C1_);
    calc_f<<<512, 256, 0, stream>>>(v2, g2, f2, O2_, O1_);
    calc_f<<<O3_, 256, 0, stream>>>(v3, g3, f3, O3_, O2_);

    transpose_scale<<<dim3((C1_ + 31) / 32, 16), dim3(32, 8), 0, stream>>>(v1, f1, Wt1, O1_, C1_, O1_);
    transpose_scale<<<dim3(16, 16), dim3(32, 8), 0, stream>>>(v2, f2, Wt2, O2_, O1_, O2_);
    transpose_scale<<<dim3(16, 1), dim3(32, 8), 0, stream>>>(v3, f3, Wt3, O3_, O2_, 16);

    gemm1<<<dim3(5, 4, B_), 256, 0, stream>>>(spike, Wt1, zA);      // zA = z1 (f64)
    scan12<<<dim3(2, B_), 256, 0, stream>>>(zA, d1, sB, sums + 0);  // sB = s1 (f32)
    gemm2<<<dim3(M_ / 64, 4), 256, 0, stream>>>(sB, Wt2, zA);       // zA = z2
    scan12<<<dim3(2, B_), 256, 0, stream>>>(zA, d2, sB, sums + 1);  // sB = s2
    gemm3<<<(M_ + 255) / 256, 256, 0, stream>>>(sB, Wt3, z3b);      // z3b = z3
    scan3<<<B_, 64, 0, stream>>>(z3b, d3, out, sums + 2);
    finalize<<<1, 64, 0, stream>>>(sums, out + (size_t)B_ * O3_ * T_);
}